// Round 2
// baseline (412.964 us; speedup 1.0000x reference)
//
#include <hip/hip_runtime.h>
#include <hip/hip_bf16.h>
#include <stdint.h>

// ImprovedLatticeRNNCell fused bf16-MFMA implementation.
// B=16384, IN=128, H=512, NH=4, HD=128.
// Plan: cvt inputs/weights -> bf16; 6 GEMMs (m97-style 128x128 tile, BK=64,
// global_load_lds width=16, mfma_f32_16x16x32_bf16) with fused epilogues;
// tiny attention + GRU elementwise kernels.

#define NB 16384
#define IND 128
#define HD2 512
#define NHEADS 4

typedef __attribute__((ext_vector_type(8))) __bf16 bf16x8;
typedef __attribute__((ext_vector_type(4))) float f32x4;
typedef __attribute__((ext_vector_type(8))) unsigned short u16x8;

__device__ __forceinline__ unsigned short f2bf(float f) {
  union { float f; unsigned int u; } v; v.f = f;
  unsigned int u = v.u;
  unsigned int r = (u + 0x7fffu + ((u >> 16) & 1u)) >> 16;
  return (unsigned short)r;
}
__device__ __forceinline__ float bf2f(unsigned short h) {
  union { unsigned int u; float f; } v; v.u = ((unsigned int)h) << 16;
  return v.f;
}
__device__ __forceinline__ float sigmoidf_(float x) {
  return 1.0f / (1.0f + __expf(-x));
}

// ---------------- convert f32 -> bf16 (8 elems/thread) ----------------
__global__ void cvt_f32_bf16(const float* __restrict__ src,
                             unsigned short* __restrict__ dst, int n8) {
  int i = blockIdx.x * blockDim.x + threadIdx.x;
  if (i >= n8) return;
  const float4* s = (const float4*)src + (size_t)i * 2;
  float4 a = s[0], b = s[1];
  u16x8 o;
  o[0] = f2bf(a.x); o[1] = f2bf(a.y); o[2] = f2bf(a.z); o[3] = f2bf(a.w);
  o[4] = f2bf(b.x); o[5] = f2bf(b.y); o[6] = f2bf(b.z); o[7] = f2bf(b.w);
  *((u16x8*)dst + i) = o;
}

// pack hidden_prev f32 [B,512] -> bf16 into gate_in [B,1536] cols 0..511
__global__ void pack_hp(const float* __restrict__ hp,
                        unsigned short* __restrict__ gate_in) {
  int t = blockIdx.x * blockDim.x + threadIdx.x;  // B*64 threads
  int b = t >> 6;
  int j = (t & 63) * 8;
  const float4* s = (const float4*)(hp + (size_t)b * 512 + j);
  float4 a = s[0], c = s[1];
  u16x8 o;
  o[0] = f2bf(a.x); o[1] = f2bf(a.y); o[2] = f2bf(a.z); o[3] = f2bf(a.w);
  o[4] = f2bf(c.x); o[5] = f2bf(c.y); o[6] = f2bf(c.z); o[7] = f2bf(c.w);
  *(u16x8*)(gate_in + (size_t)b * 1536 + j) = o;
}

// ---------------- GEMM: C[M,N] = A[M,K](bf16) * W[N,K]^T(bf16) + bias ----------------
// 128x128 tile, BK=64, 4 waves (2x2 of 64x64), mfma_f32_16x16x32_bf16.
__device__ __forceinline__ void gl_lds16(const unsigned short* g, unsigned short* l) {
  __builtin_amdgcn_global_load_lds(
      (const __attribute__((address_space(1))) void*)g,
      (__attribute__((address_space(3))) void*)l, 16, 0, 0);
}

template <int EPI>
__global__ void gemm_bt(const unsigned short* __restrict__ A, int lda,
                        const unsigned short* __restrict__ W, int ldw,
                        const float* __restrict__ bias, int K,
                        unsigned short* __restrict__ outb, int ldob,
                        float* __restrict__ outf,
                        const float* __restrict__ hp,
                        const unsigned short* __restrict__ scb) {
  __shared__ unsigned short As[128 * 64];
  __shared__ unsigned short Ws[128 * 64];
  const int tid = threadIdx.x;
  const int lane = tid & 63;
  const int wave = tid >> 6;
  const int m0 = blockIdx.y * 128;
  const int n0 = blockIdx.x * 128;
  const int wm = (wave >> 1) * 64;
  const int wn = (wave & 1) * 64;

  f32x4 acc[4][4] = {};

  const int srow = tid >> 3;        // 0..31
  const int scol = (tid & 7) * 8;   // 0,8,..,56
  const unsigned short* Ag = A + (size_t)(m0 + srow) * lda + scol;
  const unsigned short* Wg = W + (size_t)(n0 + srow) * ldw + scol;
  unsigned short* Asd = As + tid * 8;
  unsigned short* Wsd = Ws + tid * 8;

  for (int k0 = 0; k0 < K; k0 += 64) {
#pragma unroll
    for (int i = 0; i < 4; ++i) {
      gl_lds16(Ag + (size_t)(i * 32) * lda + k0, Asd + i * 2048);
      gl_lds16(Wg + (size_t)(i * 32) * ldw + k0, Wsd + i * 2048);
    }
    __syncthreads();
#pragma unroll
    for (int kk = 0; kk < 2; ++kk) {
      const int kr = kk * 32 + (lane >> 4) * 8;
      bf16x8 af[4], wf[4];
#pragma unroll
      for (int m = 0; m < 4; ++m)
        af[m] = *(const bf16x8*)&As[(wm + m * 16 + (lane & 15)) * 64 + kr];
#pragma unroll
      for (int n = 0; n < 4; ++n)
        wf[n] = *(const bf16x8*)&Ws[(wn + n * 16 + (lane & 15)) * 64 + kr];
#pragma unroll
      for (int m = 0; m < 4; ++m)
#pragma unroll
        for (int n = 0; n < 4; ++n)
          acc[m][n] = __builtin_amdgcn_mfma_f32_16x16x32_bf16(af[m], wf[n],
                                                              acc[m][n], 0, 0, 0);
    }
    __syncthreads();
  }

  const int r0 = m0 + wm + ((lane >> 4) << 2);
  const int c0 = n0 + wn + (lane & 15);
#pragma unroll
  for (int n = 0; n < 4; ++n) {
    const int col = c0 + n * 16;
    const float bv = bias ? bias[col] : 0.0f;
#pragma unroll
    for (int m = 0; m < 4; ++m) {
#pragma unroll
      for (int i = 0; i < 4; ++i) {
        const int row = r0 + m * 16 + i;
        float v = acc[m][n][i] + bv;
        if constexpr (EPI == 0) {
          outb[(size_t)row * ldob + col] = f2bf(v);
        } else {
          // gate epilogue: g = sigmoid(v); enhanced = hp + g*sc
          float g = sigmoidf_(v);
          float sc = bf2f(scb[(size_t)row * 1536 + col]);
          float e = hp[(size_t)row * 512 + col] + g * sc;
          outf[(size_t)row * 512 + col] = e;
          outb[(size_t)row * 512 + col] = f2bf(e);
        }
      }
    }
  }
}

// ---------------- attention over the 2 neighbor states ----------------
// one (row, head) per 16-lane group; ctx_mean = c0*v0 + c1*v1
__global__ void attn_fuse(const unsigned short* __restrict__ qkvl,
                          const unsigned short* __restrict__ qkvu,
                          unsigned short* __restrict__ ctx) {
  int t = blockIdx.x * blockDim.x + threadIdx.x;
  int g = t >> 4;  // (b,h)
  int l = t & 15;
  int b = g >> 2, h = g & 3;
  const size_t base = (size_t)b * 1536 + h * 128 + l * 8;
  u16x8 q0 = *(const u16x8*)(qkvl + base);
  u16x8 k0 = *(const u16x8*)(qkvl + base + 512);
  u16x8 v0 = *(const u16x8*)(qkvl + base + 1024);
  u16x8 q1 = *(const u16x8*)(qkvu + base);
  u16x8 k1 = *(const u16x8*)(qkvu + base + 512);
  u16x8 v1 = *(const u16x8*)(qkvu + base + 1024);
  float s00 = 0.f, s01 = 0.f, s10 = 0.f, s11 = 0.f;
  float v0f[8], v1f[8];
#pragma unroll
  for (int i = 0; i < 8; ++i) {
    float q0f = bf2f(q0[i]), q1f = bf2f(q1[i]);
    float k0f = bf2f(k0[i]), k1f = bf2f(k1[i]);
    v0f[i] = bf2f(v0[i]); v1f[i] = bf2f(v1[i]);
    s00 += q0f * k0f; s01 += q0f * k1f;
    s10 += q1f * k0f; s11 += q1f * k1f;
  }
#pragma unroll
  for (int off = 1; off < 16; off <<= 1) {
    s00 += __shfl_xor(s00, off);
    s01 += __shfl_xor(s01, off);
    s10 += __shfl_xor(s10, off);
    s11 += __shfl_xor(s11, off);
  }
  const float scale = 0.0883883476483184f;  // 1/sqrt(128)
  s00 *= scale; s01 *= scale; s10 *= scale; s11 *= scale;
  float m0 = fmaxf(s00, s01), m1 = fmaxf(s10, s11);
  float a00 = __expf(s00 - m0), a01 = __expf(s01 - m0);
  float a10 = __expf(s10 - m1), a11 = __expf(s11 - m1);
  float c0 = 0.5f * (a00 / (a00 + a01) + a10 / (a10 + a11));
  float c1 = 0.5f * (a01 / (a00 + a01) + a11 / (a10 + a11));
  u16x8 o;
#pragma unroll
  for (int i = 0; i < 8; ++i) o[i] = f2bf(c0 * v0f[i] + c1 * v1f[i]);
  *(u16x8*)(ctx + (size_t)b * 512 + h * 128 + l * 8) = o;
}

// ---------------- GRU elementwise finish ----------------
__global__ void gru_final(const unsigned short* __restrict__ gi,
                          const unsigned short* __restrict__ gh,
                          const float* __restrict__ enh,
                          float* __restrict__ out) {
  int t = blockIdx.x * blockDim.x + threadIdx.x;  // B*64 threads
  int b = t >> 6;
  int j = (t & 63) * 8;
  size_t gb = (size_t)b * 1536 + j;
  u16x8 ir = *(const u16x8*)(gi + gb);
  u16x8 iz = *(const u16x8*)(gi + gb + 512);
  u16x8 in_ = *(const u16x8*)(gi + gb + 1024);
  u16x8 hr = *(const u16x8*)(gh + gb);
  u16x8 hz = *(const u16x8*)(gh + gb + 512);
  u16x8 hn = *(const u16x8*)(gh + gb + 1024);
  size_t eb = (size_t)b * 512 + j;
  float4 e0 = *(const float4*)(enh + eb);
  float4 e1 = *(const float4*)(enh + eb + 4);
  float ef[8] = {e0.x, e0.y, e0.z, e0.w, e1.x, e1.y, e1.z, e1.w};
  float of[8];
#pragma unroll
  for (int i = 0; i < 8; ++i) {
    float r = sigmoidf_(bf2f(ir[i]) + bf2f(hr[i]));
    float z = sigmoidf_(bf2f(iz[i]) + bf2f(hz[i]));
    float n = tanhf(bf2f(in_[i]) + r * bf2f(hn[i]));
    of[i] = (1.0f - z) * n + z * ef[i];
  }
  *(float4*)(out + eb) = make_float4(of[0], of[1], of[2], of[3]);
  *(float4*)(out + eb + 4) = make_float4(of[4], of[5], of[6], of[7]);
}

extern "C" void kernel_launch(void* const* d_in, const int* in_sizes, int n_in,
                              void* d_out, int out_size, void* d_ws, size_t ws_size,
                              hipStream_t stream) {
  const float* x = (const float*)d_in[0];
  const float* hl = (const float*)d_in[1];
  const float* hu = (const float*)d_in[2];
  const float* hp = (const float*)d_in[3];
  const float* W_in = (const float*)d_in[4];
  const float* b_in = (const float*)d_in[5];
  const float* attn_in_w = (const float*)d_in[6];
  const float* attn_in_b = (const float*)d_in[7];
  const float* attn_out_w = (const float*)d_in[8];
  const float* attn_out_b = (const float*)d_in[9];
  const float* W_gate = (const float*)d_in[10];
  const float* b_gate = (const float*)d_in[11];
  const float* gru_w_ih = (const float*)d_in[12];
  const float* gru_w_hh = (const float*)d_in[13];
  const float* gru_b_ih = (const float*)d_in[14];
  const float* gru_b_hh = (const float*)d_in[15];

  char* ws = (char*)d_ws;
  size_t off = 0;
  auto alloc = [&](size_t bytes) {
    void* p = ws + off;
    off += (bytes + 255) & ~(size_t)255;
    return p;
  };
  // bf16 weights
  unsigned short* wWin  = (unsigned short*)alloc((size_t)512 * 128 * 2);
  unsigned short* wAin  = (unsigned short*)alloc((size_t)1536 * 512 * 2);
  unsigned short* wAout = (unsigned short*)alloc((size_t)512 * 512 * 2);
  unsigned short* wGate = (unsigned short*)alloc((size_t)512 * 1536 * 2);
  unsigned short* wIh   = (unsigned short*)alloc((size_t)1536 * 128 * 2);
  unsigned short* wHh   = (unsigned short*)alloc((size_t)1536 * 512 * 2);
  // bf16 activations
  unsigned short* xb  = (unsigned short*)alloc((size_t)NB * 128 * 2);
  unsigned short* hlb = (unsigned short*)alloc((size_t)NB * 512 * 2);
  unsigned short* hub = (unsigned short*)alloc((size_t)NB * 512 * 2);
  unsigned short* gate_in = (unsigned short*)alloc((size_t)NB * 1536 * 2);  // [hp|sc|xp]
  unsigned short* qkvl = (unsigned short*)alloc((size_t)NB * 1536 * 2);     // later gi
  unsigned short* qkvu = (unsigned short*)alloc((size_t)NB * 1536 * 2);     // later gh
  unsigned short* ctxb = (unsigned short*)alloc((size_t)NB * 512 * 2);
  float* enhf = (float*)alloc((size_t)NB * 512 * 4);
  unsigned short* enhb = (unsigned short*)alloc((size_t)NB * 512 * 2);
  unsigned short* gi = qkvl;  // reuse (qkv dead after attn_fuse)
  unsigned short* gh = qkvu;

  (void)ws_size; (void)in_sizes; (void)n_in; (void)out_size;

  const int T = 256;
  auto cvt = [&](const float* s, unsigned short* d, size_t n) {
    int n8 = (int)(n / 8);
    cvt_f32_bf16<<<(n8 + T - 1) / T, T, 0, stream>>>(s, d, n8);
  };
  // weight + activation conversions
  cvt(W_in, wWin, (size_t)512 * 128);
  cvt(attn_in_w, wAin, (size_t)1536 * 512);
  cvt(attn_out_w, wAout, (size_t)512 * 512);
  cvt(W_gate, wGate, (size_t)512 * 1536);
  cvt(gru_w_ih, wIh, (size_t)1536 * 128);
  cvt(gru_w_hh, wHh, (size_t)1536 * 512);
  cvt(x, xb, (size_t)NB * 128);
  cvt(hl, hlb, (size_t)NB * 512);
  cvt(hu, hub, (size_t)NB * 512);
  pack_hp<<<NB * 64 / T, T, 0, stream>>>(hp, gate_in);

  const int MT = NB / 128;  // 128 M-tiles
  // G1: x_proj -> gate_in cols 1024..1535
  gemm_bt<0><<<dim3(4, MT), T, 0, stream>>>(xb, 128, wWin, 128, b_in, 128,
                                            gate_in + 1024, 1536, nullptr, nullptr, nullptr);
  // G2: qkv for left/up
  gemm_bt<0><<<dim3(12, MT), T, 0, stream>>>(hlb, 512, wAin, 512, attn_in_b, 512,
                                             qkvl, 1536, nullptr, nullptr, nullptr);
  gemm_bt<0><<<dim3(12, MT), T, 0, stream>>>(hub, 512, wAin, 512, attn_in_b, 512,
                                             qkvu, 1536, nullptr, nullptr, nullptr);
  // attention -> ctx_mean (bf16)
  attn_fuse<<<NB * NHEADS * 16 / T, T, 0, stream>>>(qkvl, qkvu, ctxb);
  // G4: spatial_combined -> gate_in cols 512..1023
  gemm_bt<0><<<dim3(4, MT), T, 0, stream>>>(ctxb, 512, wAout, 512, attn_out_b, 512,
                                            gate_in + 512, 1536, nullptr, nullptr, nullptr);
  // G6: gi = x @ w_ih^T + b_ih   (into qkvl region)
  gemm_bt<0><<<dim3(12, MT), T, 0, stream>>>(xb, 128, wIh, 128, gru_b_ih, 128,
                                             gi, 1536, nullptr, nullptr, nullptr);
  // G5: gate + enhanced
  gemm_bt<1><<<dim3(4, MT), T, 0, stream>>>(gate_in, 1536, wGate, 1536, b_gate, 1536,
                                            enhb, 512, enhf, hp, gate_in + 512);
  // G7: gh = enhanced @ w_hh^T + b_hh  (into qkvu region)
  gemm_bt<0><<<dim3(12, MT), T, 0, stream>>>(enhb, 512, wHh, 512, gru_b_hh, 512,
                                             gh, 1536, nullptr, nullptr, nullptr);
  // final GRU blend
  gru_final<<<NB * 64 / T, T, 0, stream>>>(gi, gh, enhf, (float*)d_out);
}

// Round 3
// 328.928 us; speedup vs baseline: 1.2555x; 1.2555x over previous
//
#include <hip/hip_runtime.h>
#include <hip/hip_bf16.h>
#include <stdint.h>

// ImprovedLatticeRNNCell fused bf16-MFMA implementation, round 3.
// B=16384, IN=128, H=512, NH=4, HD=128.
// GEMM: 128x128 tile, BK=64, double-buffered LDS, counted vmcnt, LDS swizzle
// (pre-swizzled global source + swizzled ds_read), XCD-aware block swizzle.

#define NB 16384
#define NHEADS 4

typedef __attribute__((ext_vector_type(8))) __bf16 bf16x8;
typedef __attribute__((ext_vector_type(4))) float f32x4;
typedef __attribute__((ext_vector_type(8))) unsigned short u16x8;

__device__ __forceinline__ unsigned short f2bf(float f) {
  union { float f; unsigned int u; } v; v.f = f;
  unsigned int u = v.u;
  unsigned int r = (u + 0x7fffu + ((u >> 16) & 1u)) >> 16;
  return (unsigned short)r;
}
__device__ __forceinline__ float bf2f(unsigned short h) {
  union { unsigned int u; float f; } v; v.u = ((unsigned int)h) << 16;
  return v.f;
}
__device__ __forceinline__ float sigmoidf_(float x) {
  return 1.0f / (1.0f + __expf(-x));
}

// ---------------- convert f32 -> bf16 (8 elems/thread) ----------------
__global__ void cvt_f32_bf16(const float* __restrict__ src,
                             unsigned short* __restrict__ dst, int n8) {
  int i = blockIdx.x * blockDim.x + threadIdx.x;
  if (i >= n8) return;
  const float4* s = (const float4*)src + (size_t)i * 2;
  float4 a = s[0], b = s[1];
  u16x8 o;
  o[0] = f2bf(a.x); o[1] = f2bf(a.y); o[2] = f2bf(a.z); o[3] = f2bf(a.w);
  o[4] = f2bf(b.x); o[5] = f2bf(b.y); o[6] = f2bf(b.z); o[7] = f2bf(b.w);
  *((u16x8*)dst + i) = o;
}

// pack hidden_prev f32 [B,512] -> bf16 into gate_in [B,1536] cols 0..511
__global__ void pack_hp(const float* __restrict__ hp,
                        unsigned short* __restrict__ gate_in) {
  int t = blockIdx.x * blockDim.x + threadIdx.x;  // B*64 threads
  int b = t >> 6;
  int j = (t & 63) * 8;
  const float4* s = (const float4*)(hp + (size_t)b * 512 + j);
  float4 a = s[0], c = s[1];
  u16x8 o;
  o[0] = f2bf(a.x); o[1] = f2bf(a.y); o[2] = f2bf(a.z); o[3] = f2bf(a.w);
  o[4] = f2bf(c.x); o[5] = f2bf(c.y); o[6] = f2bf(c.z); o[7] = f2bf(c.w);
  *(u16x8*)(gate_in + (size_t)b * 1536 + j) = o;
}

// ---------------- GEMM: C[M,N] = A[M,K](bf16) * W[N,K]^T(bf16) + bias ----------------
__device__ __forceinline__ void gl_lds16(const unsigned short* g, unsigned short* l) {
  __builtin_amdgcn_global_load_lds(
      (const __attribute__((address_space(1))) void*)g,
      (__attribute__((address_space(3))) void*)l, 16, 0, 0);
}

// EPI 0: outb[row*ldob+col] = bf16(v)
// EPI 1: gate epilogue (sigmoid, enhanced blend) -> outf(f32) + outb(bf16)
// EPI 2: router: col<512 -> outb (ldob), else outb2 at col-512 (ldob2);
//        bias for branch A, bias2 for branch B.
template <int EPI>
__global__ __launch_bounds__(256, 2) void gemm_bt(
    const unsigned short* __restrict__ A, int lda,
    const unsigned short* __restrict__ W, int ldw,
    const float* __restrict__ bias, const float* __restrict__ bias2,
    int K, int ntx,
    unsigned short* __restrict__ outb, int ldob,
    unsigned short* __restrict__ outb2, int ldob2,
    float* __restrict__ outf,
    const float* __restrict__ hp,
    const unsigned short* __restrict__ scb) {
  __shared__ unsigned short As[2][128 * 64];
  __shared__ unsigned short Ws[2][128 * 64];
  const int tid = threadIdx.x;
  const int lane = tid & 63;
  const int wave = tid >> 6;

  // XCD-aware bijective swizzle (gridDim.x always a multiple of 8 here)
  const int nwg = gridDim.x;
  const int cpx = nwg >> 3;
  const int bid = blockIdx.x;
  const int id = (bid & 7) * cpx + (bid >> 3);
  const int bx = id % ntx;
  const int by = id / ntx;

  const int m0 = by * 128;
  const int n0 = bx * 128;
  const int wm = (wave >> 1) * 64;
  const int wn = (wave & 1) * 64;

  f32x4 acc[4][4] = {};

  // staging: thread covers (row=srow+32i, 16B slot sslot), source slot
  // pre-swizzled so that swizzled ds_read sees conflict-free layout.
  const int srow = tid >> 3;                     // 0..31
  const int sslot = (tid & 7) ^ (srow & 7);      // inverse-swizzled source slot
  const unsigned short* Ag = A + (size_t)(m0 + srow) * lda + sslot * 8;
  const unsigned short* Wg = W + (size_t)(n0 + srow) * ldw + sslot * 8;
  unsigned short* Asd = &As[0][tid * 8];
  unsigned short* Wsd = &Ws[0][tid * 8];

  auto stage = [&](int buf, int k0) {
#pragma unroll
    for (int i = 0; i < 4; ++i) {
      gl_lds16(Ag + (size_t)(i * 32) * lda + k0, Asd + buf * 8192 + i * 2048);
      gl_lds16(Wg + (size_t)(i * 32) * ldw + k0, Wsd + buf * 8192 + i * 2048);
    }
  };

  stage(0, 0);
  int cur = 0;
  const int lrow = lane & 15;
  const int kq = (lane >> 4) * 8;       // shorts
  const int sw = (lrow & 7) << 3;       // read-side swizzle (shorts)

  for (int k0 = 0; k0 < K; k0 += 64) {
    if (k0 + 64 < K) {
      stage(cur ^ 1, k0 + 64);
      asm volatile("s_waitcnt vmcnt(8)" ::: "memory");
    } else {
      asm volatile("s_waitcnt vmcnt(0)" ::: "memory");
    }
    __builtin_amdgcn_s_barrier();
#pragma unroll
    for (int kk = 0; kk < 2; ++kk) {
      const int kr = kk * 32 + kq;
      const int ki = kr ^ sw;
      bf16x8 af[4], wf[4];
#pragma unroll
      for (int m = 0; m < 4; ++m)
        af[m] = *(const bf16x8*)&As[cur][(wm + m * 16 + lrow) * 64 + ki];
#pragma unroll
      for (int n = 0; n < 4; ++n)
        wf[n] = *(const bf16x8*)&Ws[cur][(wn + n * 16 + lrow) * 64 + ki];
#pragma unroll
      for (int m = 0; m < 4; ++m)
#pragma unroll
        for (int n = 0; n < 4; ++n)
          acc[m][n] = __builtin_amdgcn_mfma_f32_16x16x32_bf16(af[m], wf[n],
                                                              acc[m][n], 0, 0, 0);
    }
    __builtin_amdgcn_s_barrier();
    cur ^= 1;
  }

  const int r0 = m0 + wm + ((lane >> 4) << 2);
  const int c0 = n0 + wn + lrow;

  // EPI==2 routing is uniform per block (n0 multiple of 128, split at 512)
  const unsigned short* dummy = nullptr; (void)dummy;
  unsigned short* ob = outb;
  int ld = ldob, cof = 0;
  const float* bp = bias;
  if constexpr (EPI == 2) {
    if (n0 >= 512) { ob = outb2; ld = ldob2; cof = -512; bp = bias2; }
  }

#pragma unroll
  for (int n = 0; n < 4; ++n) {
    const int col = c0 + n * 16;
    float bv;
    if constexpr (EPI == 2) bv = bp ? bp[col + cof] : 0.0f;
    else bv = bias ? bias[col] : 0.0f;
#pragma unroll
    for (int m = 0; m < 4; ++m) {
#pragma unroll
      for (int i = 0; i < 4; ++i) {
        const int row = r0 + m * 16 + i;
        float v = acc[m][n][i] + bv;
        if constexpr (EPI == 1) {
          // gate epilogue: g = sigmoid(v); enhanced = hp + g*sc
          float g = sigmoidf_(v);
          float sc = bf2f(scb[(size_t)row * 1536 + col]);
          float e = hp[(size_t)row * 512 + col] + g * sc;
          outf[(size_t)row * 512 + col] = e;
          outb[(size_t)row * 512 + col] = f2bf(e);
        } else {
          ob[(size_t)row * ld + col + cof] = f2bf(v);
        }
      }
    }
  }
}

// ---------------- attention over the 2 neighbor states ----------------
__global__ void attn_fuse(const unsigned short* __restrict__ qkvl,
                          const unsigned short* __restrict__ qkvu,
                          unsigned short* __restrict__ ctx) {
  int t = blockIdx.x * blockDim.x + threadIdx.x;
  int g = t >> 4;  // (b,h)
  int l = t & 15;
  int b = g >> 2, h = g & 3;
  const size_t base = (size_t)b * 1536 + h * 128 + l * 8;
  u16x8 q0 = *(const u16x8*)(qkvl + base);
  u16x8 k0 = *(const u16x8*)(qkvl + base + 512);
  u16x8 v0 = *(const u16x8*)(qkvl + base + 1024);
  u16x8 q1 = *(const u16x8*)(qkvu + base);
  u16x8 k1 = *(const u16x8*)(qkvu + base + 512);
  u16x8 v1 = *(const u16x8*)(qkvu + base + 1024);
  float s00 = 0.f, s01 = 0.f, s10 = 0.f, s11 = 0.f;
  float v0f[8], v1f[8];
#pragma unroll
  for (int i = 0; i < 8; ++i) {
    float q0f = bf2f(q0[i]), q1f = bf2f(q1[i]);
    float k0f = bf2f(k0[i]), k1f = bf2f(k1[i]);
    v0f[i] = bf2f(v0[i]); v1f[i] = bf2f(v1[i]);
    s00 += q0f * k0f; s01 += q0f * k1f;
    s10 += q1f * k0f; s11 += q1f * k1f;
  }
#pragma unroll
  for (int off = 1; off < 16; off <<= 1) {
    s00 += __shfl_xor(s00, off);
    s01 += __shfl_xor(s01, off);
    s10 += __shfl_xor(s10, off);
    s11 += __shfl_xor(s11, off);
  }
  const float scale = 0.0883883476483184f;  // 1/sqrt(128)
  s00 *= scale; s01 *= scale; s10 *= scale; s11 *= scale;
  float m0 = fmaxf(s00, s01), m1 = fmaxf(s10, s11);
  float a00 = __expf(s00 - m0), a01 = __expf(s01 - m0);
  float a10 = __expf(s10 - m1), a11 = __expf(s11 - m1);
  float c0 = 0.5f * (a00 / (a00 + a01) + a10 / (a10 + a11));
  float c1 = 0.5f * (a01 / (a00 + a01) + a11 / (a10 + a11));
  u16x8 o;
#pragma unroll
  for (int i = 0; i < 8; ++i) o[i] = f2bf(c0 * v0f[i] + c1 * v1f[i]);
  *(u16x8*)(ctx + (size_t)b * 512 + h * 128 + l * 8) = o;
}

// ---------------- GRU elementwise finish ----------------
__global__ void gru_final(const unsigned short* __restrict__ gi,
                          const unsigned short* __restrict__ gh,
                          const float* __restrict__ enh,
                          float* __restrict__ out) {
  int t = blockIdx.x * blockDim.x + threadIdx.x;  // B*64 threads
  int b = t >> 6;
  int j = (t & 63) * 8;
  size_t gb = (size_t)b * 1536 + j;
  u16x8 ir = *(const u16x8*)(gi + gb);
  u16x8 iz = *(const u16x8*)(gi + gb + 512);
  u16x8 in_ = *(const u16x8*)(gi + gb + 1024);
  u16x8 hr = *(const u16x8*)(gh + gb);
  u16x8 hz = *(const u16x8*)(gh + gb + 512);
  u16x8 hn = *(const u16x8*)(gh + gb + 1024);
  size_t eb = (size_t)b * 512 + j;
  float4 e0 = *(const float4*)(enh + eb);
  float4 e1 = *(const float4*)(enh + eb + 4);
  float ef[8] = {e0.x, e0.y, e0.z, e0.w, e1.x, e1.y, e1.z, e1.w};
  float of[8];
#pragma unroll
  for (int i = 0; i < 8; ++i) {
    float r = sigmoidf_(bf2f(ir[i]) + bf2f(hr[i]));
    float z = sigmoidf_(bf2f(iz[i]) + bf2f(hz[i]));
    float n = tanhf(bf2f(in_[i]) + r * bf2f(hn[i]));
    of[i] = (1.0f - z) * n + z * ef[i];
  }
  *(float4*)(out + eb) = make_float4(of[0], of[1], of[2], of[3]);
  *(float4*)(out + eb + 4) = make_float4(of[4], of[5], of[6], of[7]);
}

extern "C" void kernel_launch(void* const* d_in, const int* in_sizes, int n_in,
                              void* d_out, int out_size, void* d_ws, size_t ws_size,
                              hipStream_t stream) {
  const float* x = (const float*)d_in[0];
  const float* hl = (const float*)d_in[1];
  const float* hu = (const float*)d_in[2];
  const float* hp = (const float*)d_in[3];
  const float* W_in = (const float*)d_in[4];
  const float* b_in = (const float*)d_in[5];
  const float* attn_in_w = (const float*)d_in[6];
  const float* attn_in_b = (const float*)d_in[7];
  const float* attn_out_w = (const float*)d_in[8];
  const float* attn_out_b = (const float*)d_in[9];
  const float* W_gate = (const float*)d_in[10];
  const float* b_gate = (const float*)d_in[11];
  const float* gru_w_ih = (const float*)d_in[12];
  const float* gru_w_hh = (const float*)d_in[13];
  const float* gru_b_ih = (const float*)d_in[14];
  const float* gru_b_hh = (const float*)d_in[15];

  char* ws = (char*)d_ws;
  size_t off = 0;
  auto alloc = [&](size_t bytes) {
    void* p = ws + off;
    off += (bytes + 255) & ~(size_t)255;
    return p;
  };
  // bf16 weights
  unsigned short* wComb = (unsigned short*)alloc((size_t)2048 * 128 * 2);  // [W_in; gru_w_ih]
  unsigned short* wAin  = (unsigned short*)alloc((size_t)1536 * 512 * 2);
  unsigned short* wAout = (unsigned short*)alloc((size_t)512 * 512 * 2);
  unsigned short* wGate = (unsigned short*)alloc((size_t)512 * 1536 * 2);
  unsigned short* wHh   = (unsigned short*)alloc((size_t)1536 * 512 * 2);
  // bf16 activations
  unsigned short* xb   = (unsigned short*)alloc((size_t)NB * 128 * 2);
  unsigned short* hlub = (unsigned short*)alloc((size_t)2 * NB * 512 * 2);   // [hl; hu]
  unsigned short* gate_in = (unsigned short*)alloc((size_t)NB * 1536 * 2);   // [hp|sc|xp]
  unsigned short* qkvb = (unsigned short*)alloc((size_t)2 * NB * 1536 * 2);  // [qkvl; qkvu]
  unsigned short* ctxb = (unsigned short*)alloc((size_t)NB * 512 * 2);
  float* enhf = (float*)alloc((size_t)NB * 512 * 4);
  unsigned short* enhb = (unsigned short*)alloc((size_t)NB * 512 * 2);
  unsigned short* qkvl = qkvb;
  unsigned short* qkvu = qkvb + (size_t)NB * 1536;
  unsigned short* gi = qkvl;  // reuse (qkv dead after attn_fuse)
  unsigned short* gh = qkvu;

  (void)ws_size; (void)in_sizes; (void)n_in; (void)out_size;

  const int T = 256;
  auto cvt = [&](const float* s, unsigned short* d, size_t n) {
    int n8 = (int)(n / 8);
    cvt_f32_bf16<<<(n8 + T - 1) / T, T, 0, stream>>>(s, d, n8);
  };
  // weight + activation conversions
  cvt(W_in, wComb, (size_t)512 * 128);
  cvt(gru_w_ih, wComb + (size_t)512 * 128, (size_t)1536 * 128);
  cvt(attn_in_w, wAin, (size_t)1536 * 512);
  cvt(attn_out_w, wAout, (size_t)512 * 512);
  cvt(W_gate, wGate, (size_t)512 * 1536);
  cvt(gru_w_hh, wHh, (size_t)1536 * 512);
  cvt(x, xb, (size_t)NB * 128);
  cvt(hl, hlub, (size_t)NB * 512);
  cvt(hu, hlub + (size_t)NB * 512, (size_t)NB * 512);
  pack_hp<<<NB * 64 / T, T, 0, stream>>>(hp, gate_in);

  const int MT = NB / 128;  // 128 M-tiles

  // G2 batched: qkv for [hl;hu], M=2*NB
  gemm_bt<0><<<12 * 2 * MT, T, 0, stream>>>(hlub, 512, wAin, 512, attn_in_b,
                                            nullptr, 512, 12,
                                            qkvb, 1536, nullptr, 0,
                                            nullptr, nullptr, nullptr);
  // attention -> ctx_mean (bf16)
  attn_fuse<<<NB * NHEADS * 16 / T, T, 0, stream>>>(qkvl, qkvu, ctxb);
  // G4: spatial_combined -> gate_in cols 512..1023
  gemm_bt<0><<<4 * MT, T, 0, stream>>>(ctxb, 512, wAout, 512, attn_out_b,
                                       nullptr, 512, 4,
                                       gate_in + 512, 1536, nullptr, 0,
                                       nullptr, nullptr, nullptr);
  // G1+G6 fused: x @ [W_in; w_ih]^T, N=2048; cols<512 -> gate_in+1024, else gi
  gemm_bt<2><<<16 * MT, T, 0, stream>>>(xb, 128, wComb, 128, b_in,
                                        gru_b_ih, 128, 16,
                                        gate_in + 1024, 1536, gi, 1536,
                                        nullptr, nullptr, nullptr);
  // G5: gate + enhanced
  gemm_bt<1><<<4 * MT, T, 0, stream>>>(gate_in, 1536, wGate, 1536, b_gate,
                                       nullptr, 1536, 4,
                                       enhb, 512, nullptr, 0,
                                       enhf, hp, gate_in + 512);
  // G7: gh = enhanced @ w_hh^T + b_hh
  gemm_bt<0><<<12 * MT, T, 0, stream>>>(enhb, 512, wHh, 512, gru_b_hh,
                                        nullptr, 512, 12,
                                        gh, 1536, nullptr, 0,
                                        nullptr, nullptr, nullptr);
  // final GRU blend
  gru_final<<<NB * 64 / T, T, 0, stream>>>(gi, gh, enhf, (float*)d_out);
}